// Round 11
// baseline (3211.551 us; speedup 1.0000x reference)
//
#include <hip/hip_runtime.h>

// WeightedRGCN on MI355X. Round 11: MFMA (16x16x32 bf16) GEMMs + fully fused
// user path (3 CSR gathers + dense pass in one kernel, no uacc), post path
// 2-pass kernel. CSR build kernels are R10-verbatim (proven), pointed at
// per-relation buffers so all 4 CSRs coexist.
//
// LDS per block (512 thr): Bt 32KB (bf16x2, transposed, XOR-swizzled)
//                        + Als 8 waves x 4KB (A tile [16][128] bf16x2, swz)
//                        + bias 512B  => ~64.5KB -> 2 blocks/CU.
// Fragments (m89-verified layouts): A[row=l&15][k=8*(l>>4)+j],
// B[k same][col=l&15], C col=l&15, row=4*(l>>4)+reg.

#define N_USER 100000
#define N_POST 200000

typedef __attribute__((ext_vector_type(8))) short short8;
typedef __attribute__((ext_vector_type(4))) float floatx4;

__device__ __forceinline__ unsigned int pack2_bf16(float lo, float hi) {
    unsigned int ulo, uhi;
    __builtin_memcpy(&ulo, &lo, 4);
    __builtin_memcpy(&uhi, &hi, 4);
    unsigned int rlo = (ulo + 0x7fffu + ((ulo >> 16) & 1u)) >> 16;   // RNE
    unsigned int rhi = (uhi + 0x7fffu + ((uhi >> 16) & 1u)) >> 16;
    return (rlo & 0xffffu) | (rhi << 16);
}

// -------------------------------------------------- CSR build (R10 verbatim)
__global__ __launch_bounds__(256) void csr_hist(
        const int* __restrict__ dst, int E, int* __restrict__ cnt) {
    int i = blockIdx.x * 256 + threadIdx.x;
    int stride = gridDim.x * 256;
    for (int e = i; e < E; e += stride) atomicAdd(&cnt[dst[e]], 1);
}

#define SCAN_T 1024
#define SCAN_EPT 8
__global__ __launch_bounds__(SCAN_T) void scan_excl(int* __restrict__ a, int N) {
    __shared__ int tsum[SCAN_T];
    __shared__ int carry_s;
    int tid = threadIdx.x;
    if (tid == 0) carry_s = 0;
    __syncthreads();
    const int CH = SCAN_T * SCAN_EPT;
    for (int base = 0; base < N; base += CH) {
        int v[SCAN_EPT];
        int mysum = 0;
        int i0 = base + tid * SCAN_EPT;
#pragma unroll
        for (int j = 0; j < SCAN_EPT; ++j) {
            int i = i0 + j;
            v[j] = (i < N) ? a[i] : 0;
            mysum += v[j];
        }
        tsum[tid] = mysum;
        __syncthreads();
        for (int off = 1; off < SCAN_T; off <<= 1) {
            int t = (tid >= off) ? tsum[tid - off] : 0;
            __syncthreads();
            tsum[tid] += t;
            __syncthreads();
        }
        int carry = carry_s;
        int run = carry + tsum[tid] - mysum;
#pragma unroll
        for (int j = 0; j < SCAN_EPT; ++j) {
            int i = i0 + j;
            if (i < N) a[i] = run;
            run += v[j];
        }
        __syncthreads();
        if (tid == SCAN_T - 1) carry_s = carry + tsum[tid];
        __syncthreads();
    }
    if (tid == 0) a[N] = carry_s;
}

__global__ __launch_bounds__(256) void csr_fill(
        const int* __restrict__ src, const int* __restrict__ dst, int E,
        const int* __restrict__ rp, int* __restrict__ wcur, int* __restrict__ col) {
    int i = blockIdx.x * 256 + threadIdx.x;
    int stride = gridDim.x * 256;
    for (int e = i; e < E; e += stride) {
        int d = dst[e];
        int pos = rp[d] + atomicAdd(&wcur[d], 1);
        col[pos] = src[e];
    }
}

// ------------------------------------------------------------- MFMA pieces --
// Bt[col][k] as bf16x2 words: Bt[c*64 + (k2 ^ ((c&7)<<2))] = (B[2k2][c],B[2k2+1][c])
__device__ __forceinline__ void stage_Bt_one(const float* __restrict__ W,
                                             int* Bt, int tid) {
    for (int idx = tid; idx < 128 * 64; idx += 512) {
        int c = idx & 127, k2 = idx >> 7;
        float lo = W[(2 * k2) * 128 + c];
        float hi = W[(2 * k2 + 1) * 128 + c];
        Bt[c * 64 + (k2 ^ ((c & 7) << 2))] = pack2_bf16(lo, hi);
    }
}
__device__ __forceinline__ void stage_Bt_comb(const float* __restrict__ W0,
                                              const float* __restrict__ W1,
                                              const float* __restrict__ W2,
                                              int* Bt, int tid) {
    for (int idx = tid; idx < 128 * 64; idx += 512) {
        int c = idx & 127, k2 = idx >> 7;
        int e0 = (2 * k2) * 128 + c, e1 = (2 * k2 + 1) * 128 + c;
        float lo = 1.75f * W0[e0] + 0.7f * W1[e0] + 0.3f * W2[e0];
        float hi = 1.75f * W0[e1] + 0.7f * W1[e1] + 0.3f * W2[e1];
        Bt[c * 64 + (k2 ^ ((c & 7) << 2))] = pack2_bf16(lo, hi);
    }
}

// CSR-mean of 16 rows -> per-wave A tile (bf16x2 words, swizzled)
__device__ __forceinline__ void gather_A(const float* __restrict__ x,
                                         const int* __restrict__ rp,
                                         const int* __restrict__ col, float scale,
                                         int rowbase, int N, int lane, int* Aw) {
    for (int i = 0; i < 16; ++i) {
        int row = rowbase + i;
        float sx = 0.f, sy = 0.f;
        int deg = 0;
        if (row < N) {
            int e0 = rp[row], e1 = rp[row + 1];
            deg = e1 - e0;
            for (int e = e0; e < e1; ++e) {
                const float2* xr = (const float2*)(x + (size_t)col[e] * 128);
                float2 v = xr[lane];
                sx += v.x; sy += v.y;
            }
        }
        float inv = scale / fmaxf((float)deg, 1.f);
        Aw[i * 64 + (lane ^ ((i & 7) << 2))] = pack2_bf16(sx * inv, sy * inv);
    }
}

// dense 16 rows -> per-wave A tile
__device__ __forceinline__ void dense_A(const float* __restrict__ x,
                                        int rowbase, int N, int lane, int* Aw) {
    for (int i = 0; i < 16; ++i) {
        int row = rowbase + i;
        float vx = 0.f, vy = 0.f;
        if (row < N) {
            float2 v = ((const float2*)(x + (size_t)row * 128))[lane];
            vx = v.x; vy = v.y;
        }
        Aw[i * 64 + (lane ^ ((i & 7) << 2))] = pack2_bf16(vx, vy);
    }
}

// 32 MFMA: acc[ct] (16x16 tiles over 128 cols), K=128 in 4 steps of 32
__device__ __forceinline__ void kloop_mfma(const int* Aw, const int* Bt,
                                           int lane, floatx4 acc[8]) {
    int r16 = lane & 15, h = lane >> 4;
    int sw = (r16 & 7) << 4;
#pragma unroll
    for (int ks = 0; ks < 4; ++ks) {
        int off = (ks * 64 + h * 16) ^ sw;   // byte offset within 256B row
        short8 a = *(const short8*)((const char*)Aw + r16 * 256 + off);
#pragma unroll
        for (int ct = 0; ct < 8; ++ct) {
            short8 b = *(const short8*)((const char*)Bt + (r16 + ct * 16) * 256 + off);
            acc[ct] = __builtin_amdgcn_mfma_f32_16x16x32_bf16(a, b, acc[ct], 0, 0, 0);
        }
    }
}

// ------------------------------------------------------- fused user kernel --
// out_user = relu( 1.75*mean_re(xp)@Wl_d + 0.7*mean_fb(xp)@Wl_a
//                + 0.3*mean_soc(xu)@Wl_s + xu@(1.75WrD+0.7WrA+0.3WrS) + bc )
__global__ __launch_bounds__(512) void user_fused(
        const float* __restrict__ xu, const float* __restrict__ xp,
        const int* __restrict__ rp_re, const int* __restrict__ col_re,
        const int* __restrict__ rp_fb, const int* __restrict__ col_fb,
        const int* __restrict__ rp_soc, const int* __restrict__ col_soc,
        const float* __restrict__ Wl_d, const float* __restrict__ Wl_a,
        const float* __restrict__ Wl_s, const float* __restrict__ WrD,
        const float* __restrict__ WrA, const float* __restrict__ WrS,
        const float* __restrict__ bD, const float* __restrict__ bA,
        const float* __restrict__ bS, float* __restrict__ out) {
    __shared__ int Bt[128 * 64];
    __shared__ int Als[8][16 * 64];
    __shared__ float bcs[128];
    int tid = threadIdx.x, wave = tid >> 6, lane = tid & 63;
    if (tid < 128) bcs[tid] = 1.75f * bD[tid] + 0.7f * bA[tid] + 0.3f * bS[tid];
    int rb = blockIdx.x * 128 + wave * 16;
    floatx4 zz = {0.f, 0.f, 0.f, 0.f};
    floatx4 acc[8];
#pragma unroll
    for (int ct = 0; ct < 8; ++ct) acc[ct] = zz;

    // pass 1: re (post -> user), scale 1.75
    stage_Bt_one(Wl_d, Bt, tid);
    gather_A(xp, rp_re, col_re, 1.75f, rb, N_USER, lane, Als[wave]);
    __syncthreads();
    kloop_mfma(Als[wave], Bt, lane, acc);
    __syncthreads();
    // pass 2: fb (post -> user), scale 0.7
    stage_Bt_one(Wl_a, Bt, tid);
    gather_A(xp, rp_fb, col_fb, 0.7f, rb, N_USER, lane, Als[wave]);
    __syncthreads();
    kloop_mfma(Als[wave], Bt, lane, acc);
    __syncthreads();
    // pass 3: soc (user -> user), scale 0.3
    stage_Bt_one(Wl_s, Bt, tid);
    gather_A(xu, rp_soc, col_soc, 0.3f, rb, N_USER, lane, Als[wave]);
    __syncthreads();
    kloop_mfma(Als[wave], Bt, lane, acc);
    __syncthreads();
    // pass 4: dense xu @ combined Wr
    stage_Bt_comb(WrD, WrA, WrS, Bt, tid);
    dense_A(xu, rb, N_USER, lane, Als[wave]);
    __syncthreads();
    kloop_mfma(Als[wave], Bt, lane, acc);

    int r16 = lane & 15, h = lane >> 4;
#pragma unroll
    for (int ct = 0; ct < 8; ++ct) {
        int c = ct * 16 + r16;
        float bc = bcs[c];
#pragma unroll
        for (int r = 0; r < 4; ++r) {
            int row = rb + h * 4 + r;
            if (row < N_USER)
                out[(size_t)row * 128 + c] = fmaxf(acc[ct][r] + bc, 0.f);
        }
    }
}

// -------------------------------------------------------- fused post kernel --
// out_post = relu( mean_eng(xu)@Wl_p + xp@Wr_p + bl_p )
__global__ __launch_bounds__(512) void post_fused(
        const float* __restrict__ xu, const float* __restrict__ xp,
        const int* __restrict__ rp, const int* __restrict__ col,
        const float* __restrict__ Wl, const float* __restrict__ Wr,
        const float* __restrict__ bias, float* __restrict__ out) {
    __shared__ int Bt[128 * 64];
    __shared__ int Als[8][16 * 64];
    __shared__ float bcs[128];
    int tid = threadIdx.x, wave = tid >> 6, lane = tid & 63;
    if (tid < 128) bcs[tid] = bias[tid];
    int rb = blockIdx.x * 128 + wave * 16;
    floatx4 zz = {0.f, 0.f, 0.f, 0.f};
    floatx4 acc[8];
#pragma unroll
    for (int ct = 0; ct < 8; ++ct) acc[ct] = zz;

    // pass 1: eng gather (user -> post)
    stage_Bt_one(Wl, Bt, tid);
    gather_A(xu, rp, col, 1.0f, rb, N_POST, lane, Als[wave]);
    __syncthreads();
    kloop_mfma(Als[wave], Bt, lane, acc);
    __syncthreads();
    // pass 2: dense xp @ Wr
    stage_Bt_one(Wr, Bt, tid);
    dense_A(xp, rb, N_POST, lane, Als[wave]);
    __syncthreads();
    kloop_mfma(Als[wave], Bt, lane, acc);

    int r16 = lane & 15, h = lane >> 4;
#pragma unroll
    for (int ct = 0; ct < 8; ++ct) {
        int c = ct * 16 + r16;
        float bc = bcs[c];
#pragma unroll
        for (int r = 0; r < 4; ++r) {
            int row = rb + h * 4 + r;
            if (row < N_POST)
                out[(size_t)row * 128 + c] = fmaxf(acc[ct][r] + bc, 0.f);
        }
    }
}

// ------------------------------------------------------------------ launch --
extern "C" void kernel_launch(void* const* d_in, const int* in_sizes, int n_in,
                              void* d_out, int out_size, void* d_ws, size_t ws_size,
                              hipStream_t stream) {
    const float* x_user  = (const float*)d_in[0];
    const float* x_post  = (const float*)d_in[1];
    const int*   re_src  = (const int*)d_in[2];
    const int*   re_dst  = (const int*)d_in[3];
    const int*   fb_src  = (const int*)d_in[4];
    const int*   fb_dst  = (const int*)d_in[5];
    const int*   soc_src = (const int*)d_in[6];
    const int*   soc_dst = (const int*)d_in[7];
    const int*   eng_src = (const int*)d_in[8];
    const int*   eng_dst = (const int*)d_in[9];
    const float* Wl_d = (const float*)d_in[10];
    const float* bl_d = (const float*)d_in[11];
    const float* Wr_d = (const float*)d_in[12];
    const float* Wl_a = (const float*)d_in[13];
    const float* bl_a = (const float*)d_in[14];
    const float* Wr_a = (const float*)d_in[15];
    const float* Wl_s = (const float*)d_in[16];
    const float* bl_s = (const float*)d_in[17];
    const float* Wr_s = (const float*)d_in[18];
    const float* Wl_p = (const float*)d_in[19];
    const float* bl_p = (const float*)d_in[20];
    const float* Wr_p = (const float*)d_in[21];

    const int E_re  = in_sizes[2];
    const int E_fb  = in_sizes[4];
    const int E_soc = in_sizes[6];
    const int E_eng = in_sizes[8];

    int* ib = (int*)d_ws;
    int* rp_re   = ib;                          // N_USER+1
    int* rp_fb   = rp_re  + (N_USER + 1);
    int* rp_soc  = rp_fb  + (N_USER + 1);
    int* rp_post = rp_soc + (N_USER + 1);       // N_POST+1
    int* wcur    = rp_post + (N_POST + 1);      // N_POST
    int* col_re  = wcur + N_POST;
    int* col_fb  = col_re + E_re;
    int* col_soc = col_fb + E_fb;
    int* col_post= col_soc + E_soc;

    float* out_user = (float*)d_out;
    float* out_post = out_user + (size_t)N_USER * 128;

    auto build_csr = [&](const int* src, const int* dst, int E, int Ndst,
                         int* rp, int* col) {
        hipMemsetAsync(rp, 0, (Ndst + 1) * sizeof(int), stream);
        hipMemsetAsync(wcur, 0, Ndst * sizeof(int), stream);
        csr_hist<<<1024, 256, 0, stream>>>(dst, E, rp);
        scan_excl<<<1, SCAN_T, 0, stream>>>(rp, Ndst);
        csr_fill<<<1024, 256, 0, stream>>>(src, dst, E, rp, wcur, col);
    };

    build_csr(re_src,  re_dst,  E_re,  N_USER, rp_re,   col_re);
    build_csr(fb_src,  fb_dst,  E_fb,  N_USER, rp_fb,   col_fb);
    build_csr(soc_src, soc_dst, E_soc, N_USER, rp_soc,  col_soc);
    build_csr(eng_src, eng_dst, E_eng, N_POST, rp_post, col_post);

    const int gU = (N_USER + 127) / 128;   // 782
    const int gP = (N_POST + 127) / 128;   // 1563

    user_fused<<<gU, 512, 0, stream>>>(x_user, x_post,
                                       rp_re, col_re, rp_fb, col_fb,
                                       rp_soc, col_soc,
                                       Wl_d, Wl_a, Wl_s, Wr_d, Wr_a, Wr_s,
                                       bl_d, bl_a, bl_s, out_user);
    post_fused<<<gP, 512, 0, stream>>>(x_user, x_post, rp_post, col_post,
                                       Wl_p, Wr_p, bl_p, out_post);
}

// Round 16
// 2316.631 us; speedup vs baseline: 1.3863x; 1.3863x over previous
//
#include <hip/hip_runtime.h>

// WeightedRGCN on MI355X. Round 16: identical to round-15 source (round 15
// hit the dead pod again — resubmitting). Fix under test: R12/R14's absmax
// 4.92 was a lane->feature mapping mismatch in the interleaved gather:
// float2 loads deliver features [2*lane],[2*lane+1] but the At stores kept
// R10's scalar-load slots [lane],[lane+64] -> permuted A tile. Fix: store
// to at[(2*lane)*4+i] / at[(2*lane+1)*4+i]. Everything else = proven R10.
//
// ws layout (words), ~14.8M = 59.2 MB:
//   [0 .. 12.8M)     uacc (fp32 user accumulator)
//   [12.8M .. +1.6M) col_idx  [.. +200001) row_ptr  [.. +200K) wcur

#define N_USER 100000
#define N_POST 200000
#define DD 128
#define E_MAX 1600000

__device__ __forceinline__ unsigned int pack2_bf16(float lo, float hi) {
    unsigned int ulo, uhi;
    __builtin_memcpy(&ulo, &lo, 4);
    __builtin_memcpy(&uhi, &hi, 4);
    unsigned int rlo = (ulo + 0x7fffu + ((ulo >> 16) & 1u)) >> 16;   // RNE
    unsigned int rhi = (uhi + 0x7fffu + ((uhi >> 16) & 1u)) >> 16;
    return (rlo & 0xffffu) | (rhi << 16);
}
__device__ __forceinline__ float bf16_lo(unsigned int u) {
    unsigned int t = u << 16; float f; __builtin_memcpy(&f, &t, 4); return f;
}
__device__ __forceinline__ float bf16_hi(unsigned int u) {
    unsigned int t = u & 0xffff0000u; float f; __builtin_memcpy(&f, &t, 4); return f;
}

// -------------------------------------------------- CSR build (R10 verbatim)
__global__ __launch_bounds__(256) void csr_hist(
        const int* __restrict__ dst, int E, int* __restrict__ cnt) {
    int i = blockIdx.x * 256 + threadIdx.x;
    int stride = gridDim.x * 256;
    for (int e = i; e < E; e += stride) atomicAdd(&cnt[dst[e]], 1);
}

#define SCAN_T 1024
#define SCAN_EPT 8
__global__ __launch_bounds__(SCAN_T) void scan_excl(int* __restrict__ a, int N) {
    __shared__ int tsum[SCAN_T];
    __shared__ int carry_s;
    int tid = threadIdx.x;
    if (tid == 0) carry_s = 0;
    __syncthreads();
    const int CH = SCAN_T * SCAN_EPT;
    for (int base = 0; base < N; base += CH) {
        int v[SCAN_EPT];
        int mysum = 0;
        int i0 = base + tid * SCAN_EPT;
#pragma unroll
        for (int j = 0; j < SCAN_EPT; ++j) {
            int i = i0 + j;
            v[j] = (i < N) ? a[i] : 0;
            mysum += v[j];
        }
        tsum[tid] = mysum;
        __syncthreads();
        for (int off = 1; off < SCAN_T; off <<= 1) {
            int t = (tid >= off) ? tsum[tid - off] : 0;
            __syncthreads();
            tsum[tid] += t;
            __syncthreads();
        }
        int carry = carry_s;
        int run = carry + tsum[tid] - mysum;
#pragma unroll
        for (int j = 0; j < SCAN_EPT; ++j) {
            int i = i0 + j;
            if (i < N) a[i] = run;
            run += v[j];
        }
        __syncthreads();
        if (tid == SCAN_T - 1) carry_s = carry + tsum[tid];
        __syncthreads();
    }
    if (tid == 0) a[N] = carry_s;
}

__global__ __launch_bounds__(256) void csr_fill(
        const int* __restrict__ src, const int* __restrict__ dst, int E,
        const int* __restrict__ rp, int* __restrict__ wcur, int* __restrict__ col) {
    int i = blockIdx.x * 256 + threadIdx.x;
    int stride = gridDim.x * 256;
    for (int e = i; e < E; e += stride) {
        int d = dst[e];
        int pos = rp[d] + atomicAdd(&wcur[d], 1);
        col[pos] = src[e];
    }
}

// ------------------------------------------------------------ GEMM pieces ---
__device__ __forceinline__ void stage_B(const float* __restrict__ B,
                                        unsigned int* Bp, int tid) {
    for (int i = tid; i < 128 * 64; i += 512) {
        int k = i >> 6, j = i & 63;
        Bp[i] = pack2_bf16(B[k * 128 + j], B[k * 128 + j + 64]);
    }
}

// 4 dense rows -> per-wave transposed LDS: at[k*4+i] = A[row_i][k]
__device__ __forceinline__ void load_rows(const float* __restrict__ A,
                                          int base, int N, int lane, float* at) {
#pragma unroll
    for (int i = 0; i < 4; ++i) {
        int row = base + i;
        float a0 = 0.f, a1 = 0.f;
        if (row < N) {
            a0 = A[(size_t)row * DD + lane];
            a1 = A[(size_t)row * DD + 64 + lane];
        }
        at[lane * 4 + i] = a0;
        at[(lane + 64) * 4 + i] = a1;
    }
}

// 4 CSR-mean rows, interleaved edge loop (4 indep chains x2 unroll).
// float2 loads give features [2*lane], [2*lane+1] -> store to the MATCHING
// At slots (2*lane, 2*lane+1). R12/R14 stored to [lane],[lane+64] = the bug.
__device__ __forceinline__ void gather_rows(const float* __restrict__ x,
                                            const int* __restrict__ rp,
                                            const int* __restrict__ col, float scale,
                                            int base, int N, int lane, float* at) {
    int s0[4], dg[4];
    int maxd = 0;
#pragma unroll
    for (int i = 0; i < 4; ++i) {
        int row = base + i;
        int e0 = (row < N) ? rp[row] : 0;
        int e1 = (row < N) ? rp[row + 1] : 0;
        s0[i] = e0;
        dg[i] = e1 - e0;
        maxd = max(maxd, dg[i]);
    }
    float a0[4] = {0.f, 0.f, 0.f, 0.f};
    float a1[4] = {0.f, 0.f, 0.f, 0.f};
#pragma unroll 2
    for (int d = 0; d < maxd; ++d) {
#pragma unroll
        for (int i = 0; i < 4; ++i) {
            if (d < dg[i]) {
                const float2* xr = (const float2*)(x + (size_t)col[s0[i] + d] * DD);
                float2 v = xr[lane];
                a0[i] += v.x;
                a1[i] += v.y;
            }
        }
    }
#pragma unroll
    for (int i = 0; i < 4; ++i) {
        float inv = scale / fmaxf((float)dg[i], 1.0f);
        at[(2 * lane) * 4 + i]     = a0[i] * inv;   // feature 2*lane
        at[(2 * lane + 1) * 4 + i] = a1[i] * inv;   // feature 2*lane+1
    }
}

// unroll 4 (NOT full): full unroll spills under the 128-VGPR cap (R5 35GB).
__device__ __forceinline__ void kloop_acc(const float* at, const unsigned int* Bp,
                                          int lane, float acc[4][2]) {
#pragma unroll 4
    for (int k = 0; k < 128; ++k) {
        float4 x = *reinterpret_cast<const float4*>(at + k * 4);
        unsigned int u = Bp[k * 64 + lane];
        float b0 = bf16_lo(u), b1 = bf16_hi(u);
        acc[0][0] = fmaf(x.x, b0, acc[0][0]); acc[0][1] = fmaf(x.x, b1, acc[0][1]);
        acc[1][0] = fmaf(x.y, b0, acc[1][0]); acc[1][1] = fmaf(x.y, b1, acc[1][1]);
        acc[2][0] = fmaf(x.z, b0, acc[2][0]); acc[2][1] = fmaf(x.z, b1, acc[2][1]);
        acc[3][0] = fmaf(x.w, b0, acc[3][0]); acc[3][1] = fmaf(x.w, b1, acc[3][1]);
    }
}

// Y += scale * csr_mean(x) @ B   (pull aggregation fused with GEMM)
__global__ __launch_bounds__(512) void pull_gemm_acc(
        const float* __restrict__ x, const int* __restrict__ rp,
        const int* __restrict__ col, const float* __restrict__ B,
        float scale, float* __restrict__ Y, int N) {
    __shared__ unsigned int Bp[128 * 64];
    __shared__ __align__(16) float At[8][512];
    stage_B(B, Bp, threadIdx.x);
    __syncthreads();
    int wave = threadIdx.x >> 6, lane = threadIdx.x & 63;
    int base = (blockIdx.x * 8 + wave) * 4;
    float acc[4][2] = {{0.f,0.f},{0.f,0.f},{0.f,0.f},{0.f,0.f}};
    gather_rows(x, rp, col, scale, base, N, lane, At[wave]);
    kloop_acc(At[wave], Bp, lane, acc);
#pragma unroll
    for (int i = 0; i < 4; ++i) {
        int row = base + i;
        if (row < N) {
            float* y = Y + (size_t)row * DD + lane;
            y[0]  += acc[i][0];
            y[64] += acc[i][1];
        }
    }
}

// out_user = relu(uacc + xU @ (1.75 WrD + 0.7 WrA + 0.3 WrS) + b_comb) [fp32]
__global__ __launch_bounds__(512) void user_final_kernel(
        const float* __restrict__ uacc, const float* __restrict__ xu,
        const float* __restrict__ WrD, const float* __restrict__ WrA,
        const float* __restrict__ WrS, const float* __restrict__ bD,
        const float* __restrict__ bA, const float* __restrict__ bS,
        float* __restrict__ out, int N) {
    __shared__ unsigned int Bp[128 * 64];
    __shared__ __align__(16) float At[8][512];
    for (int i = threadIdx.x; i < 128 * 64; i += 512) {
        int k = i >> 6, j = i & 63;
        float lo = 1.75f * WrD[k*128+j]    + 0.7f * WrA[k*128+j]    + 0.3f * WrS[k*128+j];
        float hi = 1.75f * WrD[k*128+j+64] + 0.7f * WrA[k*128+j+64] + 0.3f * WrS[k*128+j+64];
        Bp[i] = pack2_bf16(lo, hi);
    }
    __syncthreads();
    int wave = threadIdx.x >> 6, lane = threadIdx.x & 63;
    int base = (blockIdx.x * 8 + wave) * 4;
    float acc[4][2] = {{0.f,0.f},{0.f,0.f},{0.f,0.f},{0.f,0.f}};
    load_rows(xu, base, N, lane, At[wave]);
    kloop_acc(At[wave], Bp, lane, acc);
    float bc0 = 1.75f*bD[lane]    + 0.7f*bA[lane]    + 0.3f*bS[lane];
    float bc1 = 1.75f*bD[lane+64] + 0.7f*bA[lane+64] + 0.3f*bS[lane+64];
#pragma unroll
    for (int i = 0; i < 4; ++i) {
        int row = base + i;
        if (row < N) {
            const float* u = uacc + (size_t)row * DD + lane;
            out[(size_t)row * DD + lane]      = fmaxf(u[0]  + acc[i][0] + bc0, 0.f);
            out[(size_t)row * DD + lane + 64] = fmaxf(u[64] + acc[i][1] + bc1, 0.f);
        }
    }
}

// out_post = relu(csr_mean(xu) @ Wl + xP @ Wr + b)  [fp32]; two staged passes.
__global__ __launch_bounds__(512) void post_final_kernel(
        const float* __restrict__ xu, const int* __restrict__ rp,
        const int* __restrict__ col, const float* __restrict__ xp,
        const float* __restrict__ Wl, const float* __restrict__ Wr,
        const float* __restrict__ bias, float* __restrict__ out, int N) {
    __shared__ unsigned int Bp[128 * 64];
    __shared__ __align__(16) float At[8][512];
    int wave = threadIdx.x >> 6, lane = threadIdx.x & 63;
    int base = (blockIdx.x * 8 + wave) * 4;
    float acc[4][2] = {{0.f,0.f},{0.f,0.f},{0.f,0.f},{0.f,0.f}};
    // pass 1: csr_mean(xu) @ Wl
    stage_B(Wl, Bp, threadIdx.x);
    __syncthreads();
    gather_rows(xu, rp, col, 1.0f, base, N, lane, At[wave]);
    kloop_acc(At[wave], Bp, lane, acc);
    __syncthreads();               // all waves done reading Bp(Wl)
    // pass 2: xp @ Wr
    stage_B(Wr, Bp, threadIdx.x);
    __syncthreads();
    load_rows(xp, base, N, lane, At[wave]);
    kloop_acc(At[wave], Bp, lane, acc);
    float b0 = bias[lane], b1 = bias[lane + 64];
#pragma unroll
    for (int i = 0; i < 4; ++i) {
        int row = base + i;
        if (row < N) {
            out[(size_t)row * DD + lane]      = fmaxf(acc[i][0] + b0, 0.f);
            out[(size_t)row * DD + lane + 64] = fmaxf(acc[i][1] + b1, 0.f);
        }
    }
}

// ------------------------------------------------------------------ launch --
extern "C" void kernel_launch(void* const* d_in, const int* in_sizes, int n_in,
                              void* d_out, int out_size, void* d_ws, size_t ws_size,
                              hipStream_t stream) {
    const float* x_user  = (const float*)d_in[0];
    const float* x_post  = (const float*)d_in[1];
    const int*   re_src  = (const int*)d_in[2];
    const int*   re_dst  = (const int*)d_in[3];
    const int*   fb_src  = (const int*)d_in[4];
    const int*   fb_dst  = (const int*)d_in[5];
    const int*   soc_src = (const int*)d_in[6];
    const int*   soc_dst = (const int*)d_in[7];
    const int*   eng_src = (const int*)d_in[8];
    const int*   eng_dst = (const int*)d_in[9];
    const float* Wl_d = (const float*)d_in[10];
    const float* bl_d = (const float*)d_in[11];
    const float* Wr_d = (const float*)d_in[12];
    const float* Wl_a = (const float*)d_in[13];
    const float* bl_a = (const float*)d_in[14];
    const float* Wr_a = (const float*)d_in[15];
    const float* Wl_s = (const float*)d_in[16];
    const float* bl_s = (const float*)d_in[17];
    const float* Wr_s = (const float*)d_in[18];
    const float* Wl_p = (const float*)d_in[19];
    const float* bl_p = (const float*)d_in[20];
    const float* Wr_p = (const float*)d_in[21];

    const int E_re  = in_sizes[2];
    const int E_fb  = in_sizes[4];
    const int E_soc = in_sizes[6];
    const int E_eng = in_sizes[8];

    float* uacc    = (float*)d_ws;                               // 12.8M floats
    int*   col_idx = (int*)((float*)d_ws + (size_t)N_USER * DD); // 1.6M ints
    int*   row_ptr = col_idx + E_MAX;                            // 200001 ints
    int*   wcur    = row_ptr + (N_POST + 1);                     // 200000 ints

    float* out_user = (float*)d_out;
    float* out_post = out_user + (size_t)N_USER * 128;

    const int gU = (N_USER + 31) / 32;   // 3125 blocks * 32 rows
    const int gP = (N_POST + 31) / 32;   // 6250 blocks * 32 rows

    auto build_csr = [&](const int* src, const int* dst, int E, int Ndst) {
        hipMemsetAsync(row_ptr, 0, (Ndst + 1) * sizeof(int), stream);
        hipMemsetAsync(wcur, 0, Ndst * sizeof(int), stream);
        csr_hist<<<1024, 256, 0, stream>>>(dst, E, row_ptr);
        scan_excl<<<1, SCAN_T, 0, stream>>>(row_ptr, Ndst);
        csr_fill<<<1024, 256, 0, stream>>>(src, dst, E, row_ptr, wcur, col_idx);
    };

    hipMemsetAsync(uacc, 0, (size_t)N_USER * DD * sizeof(float), stream);

    // ---- user: direct (re: post -> user) ----
    build_csr(re_src, re_dst, E_re, N_USER);
    pull_gemm_acc<<<gU, 512, 0, stream>>>(x_post, row_ptr, col_idx, Wl_d, 1.75f, uacc, N_USER);

    // ---- user: author (fb: post -> user) ----
    build_csr(fb_src, fb_dst, E_fb, N_USER);
    pull_gemm_acc<<<gU, 512, 0, stream>>>(x_post, row_ptr, col_idx, Wl_a, 0.7f, uacc, N_USER);

    // ---- user: social (soc: user -> user) ----
    build_csr(soc_src, soc_dst, E_soc, N_USER);
    pull_gemm_acc<<<gU, 512, 0, stream>>>(x_user, row_ptr, col_idx, Wl_s, 0.3f, uacc, N_USER);

    // ---- user output ----
    user_final_kernel<<<gU, 512, 0, stream>>>(uacc, x_user, Wr_d, Wr_a, Wr_s,
                                              bl_d, bl_a, bl_s, out_user, N_USER);

    // ---- post: eng (user -> post) ----
    build_csr(eng_src, eng_dst, E_eng, N_POST);
    post_final_kernel<<<gP, 512, 0, stream>>>(x_user, row_ptr, col_idx, x_post,
                                              Wl_p, Wr_p, bl_p, out_post, N_POST);
}